// Round 4
// baseline (125.879 us; speedup 1.0000x reference)
//
#include <hip/hip_runtime.h>
#include <math.h>

#define NCH   64
#define IMW   512
#define NPTS  150000
#define TOTAL (2 * NPTS)
#define IMHW  (512 * 512)
#define HID   32
#define NBINS 32768   // 2 batches x 512 y x 32 x-cells (16 px = one 64B line)

// ---------- sort pass ----------

__global__ __launch_bounds__(256) void hist_kernel(const int* __restrict__ coords,
                                                   int* __restrict__ hist) {
    int gid = blockIdx.x * blockDim.x + threadIdx.x;
    if (gid >= TOTAL) return;
    const int y = coords[gid * 3 + 1];
    const int x = coords[gid * 3 + 2];
    const int b = (gid >= NPTS) ? 1 : 0;
    const int key = (b << 14) | (y << 5) | (x >> 4);
    atomicAdd(&hist[key], 1);
}

// single-block exclusive scan of 32768 ints (1024 thr x 32 each)
__global__ __launch_bounds__(1024) void scan_kernel(const int* __restrict__ hist,
                                                    int* __restrict__ binPos) {
    __shared__ int lds[1024];
    const int t = threadIdx.x;
    const int base = t * 32;
    int loc[32];
    int s = 0;
    #pragma unroll
    for (int i = 0; i < 32; ++i) { loc[i] = s; s += hist[base + i]; }
    lds[t] = s;
    __syncthreads();
    for (int d = 1; d < 1024; d <<= 1) {
        int v = lds[t];
        int add = (t >= d) ? lds[t - d] : 0;
        __syncthreads();
        lds[t] = v + add;
        __syncthreads();
    }
    const int excl = lds[t] - s;
    #pragma unroll
    for (int i = 0; i < 32; ++i) binPos[base + i] = excl + loc[i];
}

__global__ __launch_bounds__(256) void scatter_kernel(const int* __restrict__ coords,
                                                      int* __restrict__ binPos,
                                                      int* __restrict__ perm) {
    int gid = blockIdx.x * blockDim.x + threadIdx.x;
    if (gid >= TOTAL) return;
    const int y = coords[gid * 3 + 1];
    const int x = coords[gid * 3 + 2];
    const int b = (gid >= NPTS) ? 1 : 0;
    const int key = (b << 14) | (y << 5) | (x >> 4);
    const int pos = atomicAdd(&binPos[key], 1);
    perm[pos] = gid;
}

// ---------- fused gather + MLP: 4 waves/block, wave w = channel-group w ----------
// block = 256 threads = 4 waves; block handles 64 points (one per lane).
// wave w reads 32 channels: w=0,1 -> before[ w*32 .. ], w=2,3 -> after[ (w-2)*32 .. ]
// -> W1 rows (w*32+j) are wave-uniform -> scalar broadcast weights.
// All 32 gathers issued upfront per thread -> 32-deep vmem pipeline.

__global__ __launch_bounds__(256) void ffd_kernel(
    const float* __restrict__ before,
    const float* __restrict__ after,
    const float* __restrict__ offsets,
    const int*   __restrict__ coords,
    const float* __restrict__ W1,   // [131, 32]
    const float* __restrict__ b1,   // [32]
    const float* __restrict__ W2,   // [32, 3]
    const float* __restrict__ b2,   // [3]
    const int*   __restrict__ perm, // sorted point order (or null)
    float*       __restrict__ out)  // [2, 150000, 3]
{
    __shared__ float xch[3][HID][64];   // partials from waves 1..3

    const int lane = threadIdx.x & 63;
    const int w    = __builtin_amdgcn_readfirstlane(threadIdx.x >> 6);  // 0..3
    int gpt = blockIdx.x * 64 + lane;
    const bool valid = gpt < TOTAL;
    if (!valid) gpt = TOTAL - 1;         // clamp: compute garbage, don't store

    const int pid = perm ? perm[gpt] : gpt;
    const long pbase = (long)pid * 3;

    const int y = coords[pbase + 1];
    const int x = coords[pbase + 2];
    const int b = (pid >= NPTS) ? 1 : 0;

    const float* ibase  = (w < 2) ? before : after;
    const float* img_ptr = ibase + (long)b * NCH * IMHW
                         + (long)(w & 1) * 32 * IMHW
                         + (long)y * IMW + x;
    const float* w1b = W1 + w * 32 * HID;   // rows w*32 .. w*32+31 (wave-uniform)

    // issue ALL 32 gathers before any FMA (32-deep pipeline)
    float g[32];
    #pragma unroll
    for (int j = 0; j < 32; ++j) g[j] = img_ptr[(long)j * IMHW];

    float acc[HID];
    if (w == 0) {
        const float o0 = offsets[pbase];
        const float o1 = offsets[pbase + 1];
        const float o2 = offsets[pbase + 2];
        const float* r0 = W1 + 128 * HID;
        const float* r1 = W1 + 129 * HID;
        const float* r2 = W1 + 130 * HID;
        #pragma unroll
        for (int h = 0; h < HID; ++h)
            acc[h] = fmaf(o2, r2[h], fmaf(o1, r1[h], fmaf(o0, r0[h], b1[h])));
    } else {
        #pragma unroll
        for (int h = 0; h < HID; ++h) acc[h] = 0.f;
    }

    // consume in issue order -> staged vmcnt waits
    #pragma unroll
    for (int j = 0; j < 32; ++j) {
        const float* wr = w1b + j * HID;
        #pragma unroll
        for (int h = 0; h < HID; ++h) acc[h] = fmaf(g[j], wr[h], acc[h]);
    }

    if (w > 0) {
        #pragma unroll
        for (int h = 0; h < HID; ++h) xch[w - 1][h][lane] = acc[h];
    }
    __syncthreads();

    if (w == 0 && valid) {
        #pragma unroll
        for (int h = 0; h < HID; ++h)
            acc[h] += xch[0][h][lane] + xch[1][h][lane] + xch[2][h][lane];

        #pragma unroll
        for (int h = 0; h < HID; ++h) {
            const float xh = acc[h];
            acc[h] = 0.5f * xh * (1.0f + erff(xh * 0.70710678118654752f));
        }

        float o0 = b2[0], o1 = b2[1], o2 = b2[2];
        #pragma unroll
        for (int h = 0; h < HID; ++h) {
            o0 = fmaf(acc[h], W2[h * 3 + 0], o0);
            o1 = fmaf(acc[h], W2[h * 3 + 1], o1);
            o2 = fmaf(acc[h], W2[h * 3 + 2], o2);
        }
        out[pbase + 0] = o0;
        out[pbase + 1] = o1;
        out[pbase + 2] = o2;
    }
}

extern "C" void kernel_launch(void* const* d_in, const int* in_sizes, int n_in,
                              void* d_out, int out_size, void* d_ws, size_t ws_size,
                              hipStream_t stream) {
    const float* before  = (const float*)d_in[0];
    const float* after   = (const float*)d_in[1];
    const float* offsets = (const float*)d_in[2];
    const int*   coords  = (const int*)  d_in[3];
    const float* W1      = (const float*)d_in[4];
    const float* b1      = (const float*)d_in[5];
    const float* W2      = (const float*)d_in[6];
    const float* b2      = (const float*)d_in[7];
    float* out = (float*)d_out;

    const int block = 256;
    const int sgrid = (TOTAL + block - 1) / block;
    const int fgrid = (TOTAL + 63) / 64;   // 64 points per block, 4 threads/point

    // ws layout: hist[NBINS] | binPos[NBINS] | perm[TOTAL]
    const size_t need = (size_t)(2 * NBINS + TOTAL) * sizeof(int);

    if (ws_size >= need) {
        int* hist   = (int*)d_ws;
        int* binPos = hist + NBINS;
        int* perm   = binPos + NBINS;

        hipMemsetAsync(hist, 0, NBINS * sizeof(int), stream);
        hist_kernel<<<sgrid, block, 0, stream>>>(coords, hist);
        scan_kernel<<<1, 1024, 0, stream>>>(hist, binPos);
        scatter_kernel<<<sgrid, block, 0, stream>>>(coords, binPos, perm);
        ffd_kernel<<<fgrid, block, 0, stream>>>(before, after, offsets, coords,
                                                W1, b1, W2, b2, perm, out);
    } else {
        ffd_kernel<<<fgrid, block, 0, stream>>>(before, after, offsets, coords,
                                                W1, b1, W2, b2, nullptr, out);
    }
}